// Round 7
// baseline (389.691 us; speedup 1.0000x reference)
//
#include <hip/hip_runtime.h>
#include <stdint.h>

// DomainAttentionLayer: out = softmax((x Wq^T + bq)(dx Wk^T + bk)^T / sqrt(D)) (dx Wv^T + bv)
// N = M = 8192, D = 512, fp32 in/out; internal compute bf16 MFMA.
//
// Pipeline:
//   0) prep_w    : W fp32 -> bf16 (once)
//   1) qkv_proj  : bf16 GEMMs, bias fused; Q pre-scaled by log2(e)/sqrt(D); V stored VT[D][M]
//   2) flash_attn: fused online-softmax attention, split-m partials.
//                  R7: BM=32, K AND VT double-buffered in LDS (141.9 KB, 1 block/CU,
//                  512 thr). 2 barriers/iter; DMAs for it+1 issued right after BAR_A
//                  into the idle buffers, drained at BAR_B after a full S-phase
//                  window -> staging latency hidden (R3/R6 exposed it).
//   3) combine   : exact log-sum-exp merge of partials -> fp32 out

#define DEV __device__ __forceinline__

typedef short short8 __attribute__((ext_vector_type(8)));     // 8 bf16 (4 VGPRs) MFMA frag
typedef float floatx4 __attribute__((ext_vector_type(4)));    // MFMA accum
typedef unsigned int uintx4 __attribute__((ext_vector_type(4)));
typedef unsigned short ushortx4 __attribute__((ext_vector_type(4)));

constexpr int NN = 8192;
constexpr int MM = 8192;
constexpr int DD = 512;
constexpr float SCALE2 = 0.0637587160f;         // log2(e) / sqrt(512), folded into Q

#define NEG_INF (-__builtin_inff())

#if defined(__has_builtin)
#if __has_builtin(__builtin_amdgcn_exp2f)
#define EXP2F(x) __builtin_amdgcn_exp2f(x)
#else
#define EXP2F(x) exp2f(x)
#endif
#else
#define EXP2F(x) exp2f(x)
#endif

DEV unsigned short f2bf(float f) {              // RNE fp32 -> bf16 bits
  unsigned u = __builtin_bit_cast(unsigned, f);
  return (unsigned short)((u + 0x7FFFu + ((u >> 16) & 1u)) >> 16);
}
DEV float bf2f(unsigned short h) {
  unsigned u = ((unsigned)h) << 16;
  return __builtin_bit_cast(float, u);
}

// TBAA-safe vector ld/st (memcpy compiles to single b128/b64 with assumed alignment)
DEV short8 ld_s8(const void* p) {
  short8 v; __builtin_memcpy(&v, __builtin_assume_aligned(p, 16), 16); return v;
}
DEV uintx4 ld_u4(const void* p) {
  uintx4 v; __builtin_memcpy(&v, __builtin_assume_aligned(p, 16), 16); return v;
}
DEV void st_u4(void* p, uintx4 v) {
  __builtin_memcpy(__builtin_assume_aligned(p, 16), &v, 16);
}
DEV void st_us4(void* p, ushortx4 v) {
  __builtin_memcpy(__builtin_assume_aligned(p, 8), &v, 8);
}
DEV float4 ld_f4(const void* p) {
  float4 v; __builtin_memcpy(&v, __builtin_assume_aligned(p, 16), 16); return v;
}

DEV void async_lds16(const void* g, const void* l) {  // global -> LDS DMA, 16B/lane
  __builtin_amdgcn_global_load_lds(
      (const __attribute__((address_space(1))) unsigned int*)g,
      (__attribute__((address_space(3))) unsigned int*)l, 16, 0, 0);
}

// ---------------------------------------------------------------------------
// Kernel 0: W fp32 -> bf16, once. grid (128, 1, 3), block 256, 8 elems/thread.
// ---------------------------------------------------------------------------
__global__ void prep_w(const float* __restrict__ Wq, const float* __restrict__ Wk,
                       const float* __restrict__ Wv, unsigned short* __restrict__ Wb) {
  const int z = blockIdx.z;
  const float* src = (z == 0) ? Wq : (z == 1) ? Wk : Wv;
  unsigned short* dst = Wb + (size_t)z * DD * DD;
  size_t idx = ((size_t)blockIdx.x * 256 + threadIdx.x) * 8;
  float4 a = ld_f4(src + idx);
  float4 b = ld_f4(src + idx + 4);
  ushortx4 lo = {f2bf(a.x), f2bf(a.y), f2bf(a.z), f2bf(a.w)};
  ushortx4 hi = {f2bf(b.x), f2bf(b.y), f2bf(b.z), f2bf(b.w)};
  st_us4(dst + idx, lo);
  st_us4(dst + idx + 4, hi);
}

// ---------------------------------------------------------------------------
// Kernel 1: QKV projection. grid (128, 2, 3), block 256. Tile 64 rows x 256 cols,
// BK=64. LDS xor-swizzled (chunk ^= row&7) -> conflict-free b128 frag reads.
// z=0: Q (scaled by SCALE2) -> Qb[N][D]; z=1: K -> Kb[M][D]; z=2: V -> VTb[D][M].
// ---------------------------------------------------------------------------
__global__ __launch_bounds__(256, 2)
void qkv_proj(const float* __restrict__ x, const float* __restrict__ dx,
              const unsigned short* __restrict__ Wb,
              const float* __restrict__ bq, const float* __restrict__ bk,
              const float* __restrict__ bv,
              unsigned short* __restrict__ Qb, unsigned short* __restrict__ Kb,
              unsigned short* __restrict__ VTb) {
  const int z = blockIdx.z;
  const float* A = (z == 0) ? x : dx;
  const unsigned short* W = Wb + (size_t)z * DD * DD;
  const float* bias = (z == 0) ? bq : (z == 1) ? bk : bv;

  const int r0 = blockIdx.x * 64;
  const int c0 = blockIdx.y * 256;
  const int tid = threadIdx.x;
  const int lane = tid & 63;
  const int wave = tid >> 6;
  const int lr = lane & 15;
  const int quad = lane >> 4;

  __shared__ __align__(16) unsigned short As[64 * 64];   //  8 KB
  __shared__ __align__(16) unsigned short Ws[256 * 64];  // 32 KB

  floatx4 o[16];
#pragma unroll
  for (int i = 0; i < 16; ++i) o[i] = {0.f, 0.f, 0.f, 0.f};

  for (int k0 = 0; k0 < DD; k0 += 64) {
    // stage A tile (fp32 -> bf16): 64 rows x 64 k, 4 float4 per thread
#pragma unroll
    for (int i = 0; i < 4; ++i) {
      int idx = i * 256 + tid;
      int r = idx >> 4, c4 = idx & 15;
      float4 v = ld_f4(A + (size_t)(r0 + r) * DD + k0 + c4 * 4);
      ushortx4 pk = {f2bf(v.x), f2bf(v.y), f2bf(v.z), f2bf(v.w)};
      st_us4(&As[r * 64 + (((c4 >> 1) ^ (r & 7)) * 8) + (c4 & 1) * 4], pk);
    }
    // stage W tile (bf16, no convert): 256 rows x 64 k, 8 x 16B per thread
#pragma unroll
    for (int i = 0; i < 8; ++i) {
      int idx = i * 256 + tid;
      int r = idx >> 3, c = idx & 7;
      uintx4 v = ld_u4(W + (size_t)(c0 + r) * DD + k0 + c * 8);
      st_u4(&Ws[r * 64 + ((c ^ (r & 7)) * 8)], v);
    }
    __syncthreads();

    short8 a[2];
#pragma unroll
    for (int ks = 0; ks < 2; ++ks)
      a[ks] = ld_s8(&As[(wave * 16 + lr) * 64 + (((ks * 4 + quad) ^ (lr & 7)) * 8)]);
#pragma unroll
    for (int ct = 0; ct < 16; ++ct) {
#pragma unroll
      for (int ks = 0; ks < 2; ++ks) {
        short8 b = ld_s8(&Ws[(ct * 16 + lr) * 64 + (((ks * 4 + quad) ^ (lr & 7)) * 8)]);
        o[ct] = __builtin_amdgcn_mfma_f32_16x16x32_bf16(a[ks], b, o[ct], 0, 0, 0);
      }
    }
    __syncthreads();
  }

  // epilogue: bias (+Q scale), store. C layout: col = lr, row = quad*4 + reg.
#pragma unroll
  for (int ct = 0; ct < 16; ++ct) {
    int col = c0 + ct * 16 + lr;
    float bv_ = bias[col];
    int rowb = r0 + wave * 16 + quad * 4;
    if (z == 2) {  // VT[col][row], 4 consecutive rows -> 8B store
      ushortx4 pk = {f2bf(o[ct][0] + bv_), f2bf(o[ct][1] + bv_),
                     f2bf(o[ct][2] + bv_), f2bf(o[ct][3] + bv_)};
      st_us4(VTb + (size_t)col * MM + rowb, pk);
    } else {
      unsigned short* Outp = (z == 0) ? Qb : Kb;
      float sc = (z == 0) ? SCALE2 : 1.f;
#pragma unroll
      for (int r = 0; r < 4; ++r)
        Outp[(size_t)(rowb + r) * DD + col] = f2bf((o[ct][r] + bv_) * sc);
    }
  }
}

// ---------------------------------------------------------------------------
// Kernel 2: flash attention. 1-D grid (N/128 * SPLITS_), block 512 (8 waves),
// 1 block/CU (LDS 141,856 B). split = lin & (SPLITS_-1): round-robin XCD = lin%8
// pins each XCD to one split -> its K slice is L2-resident.
// Per iter (BM=32, BN=128):
//   BAR_A (pure sync: DMAs already drained at prior BAR_B)
//   issue K(it+1) + VT(it+1) DMA into the idle halves of the double buffers
//     (their previous readers finished a full phase ago -> race-free)
//   S(it) = Q K^T from sK[it&1] (wave w: its 16 q-rows x 32 m); softmax;
//     P -> sP, alphas/flags -> LDS
//   BAR_B: publishes sP; drains DMA(it+1) after a full S-phase window (hidden)
//   rescale O (flag-gated); PV from sP + sVT[it&1] (d-split: wave w covers
//     d-cols 64w..64w+64 x all 128 q-rows)
// ---------------------------------------------------------------------------
template <int SPLITS_, int LOG2S_>
__global__ __launch_bounds__(512, 2)
void flash_attn(const unsigned short* __restrict__ Qb,
                const unsigned short* __restrict__ Kb,
                const unsigned short* __restrict__ VTb,
                unsigned short* __restrict__ Opart,
                float* __restrict__ Mpart, float* __restrict__ Lpart) {
  constexpr int MT = MM / SPLITS_;
  constexpr int ITERS = MT / 32;
  const int lin = blockIdx.x;
  const int split = lin & (SPLITS_ - 1);
  const int n0 = (lin >> LOG2S_) * 128;
  const int m_begin = split * MT;

  const int tid = threadIdx.x;
  const int lane = tid & 63;
  const int wave = tid >> 6;   // 0..7
  const int lr = lane & 15;
  const int quad = lane >> 4;

  // sK rows: 1024B K-row + 16B pad (stride 520 us) -> uniform frag-read banks.
  // sVT rows: 32 us, no pad needed (lr*16 mod 32 start pattern is uniform);
  // DMA dest = contiguous 16-row groups (1024 B per wave instr).
  __shared__ __align__(16) unsigned short sK[2][32 * 520];   // 66,560 B
  __shared__ __align__(16) unsigned short sVT[2][512 * 32];  // 65,536 B
  __shared__ __align__(16) unsigned short sP[128 * 36];      //  9,216 B
  __shared__ __align__(16) float sAlpha[128];                //    512 B
  __shared__ int sFlag[8];                                   //     32 B

  // resident Q fragments: wave's 16 rows x 512 k (64 VGPRs), pre-scaled by SCALE2
  short8 qf[16];
  {
    const unsigned short* qptr = Qb + (size_t)(n0 + wave * 16 + lr) * DD + quad * 8;
#pragma unroll
    for (int ks = 0; ks < 16; ++ks) qf[ks] = ld_s8(qptr + ks * 32);
  }

  floatx4 o[32];  // [rt*4+ct] : O rows n0+rt*16+quad*4+reg, col wave*64+ct*16+lr
#pragma unroll
  for (int i = 0; i < 32; ++i) o[i] = {0.f, 0.f, 0.f, 0.f};
  float mrow[4] = {NEG_INF, NEG_INF, NEG_INF, NEG_INF};
  float lrow[4] = {0.f, 0.f, 0.f, 0.f};

  // staging: K = 32 rows (4/wave, 1024B DMA each); VT = 512 rows of 64B in 32
  // 16-row groups (4 groups/wave; lane i -> row g*16+(i>>2), chunk i&3).
  const int vr = lane >> 2;      // row within 16-group
  const int vc = (lane & 3) * 8; // m-chunk (us)

  auto stage = [&](int m0, int buf) {
#pragma unroll
    for (int i = 0; i < 4; ++i) {
      const int r = wave * 4 + i;
      async_lds16(Kb + (size_t)(m0 + r) * DD + lane * 8, &sK[buf][r * 520]);
    }
#pragma unroll
    for (int i = 0; i < 4; ++i) {
      const int g = wave * 4 + i;
      async_lds16(VTb + (size_t)(g * 16 + vr) * MM + m0 + vc, &sVT[buf][g * 512]);
    }
  };

  stage(m_begin, 0);  // prologue

  for (int it = 0; it < ITERS; ++it) {
    const int m0 = m_begin + it * 32;

    __syncthreads();  // BAR_A: pure sync (DMA(it) drained at prior BAR_B /
                      // prologue drained at first BAR_B)... also PV(it-1) done.

    if (it + 1 < ITERS) stage(m0 + 32, (it + 1) & 1);  // into idle buffers

    // ---- S = Q K^T (wave: its 16 rows x 32 cols), logits in log2 units
    const unsigned short* kb = sK[it & 1];
    floatx4 s[2];
    s[0] = {0.f, 0.f, 0.f, 0.f};
    s[1] = {0.f, 0.f, 0.f, 0.f};
    if (it == 0) __syncthreads();  // first iter: drain prologue DMA
#pragma unroll
    for (int ks = 0; ks < 16; ++ks) {
      const unsigned short* kp = &kb[ks * 32 + quad * 8];
#pragma unroll
      for (int ct = 0; ct < 2; ++ct) {
        short8 b = ld_s8(kp + (ct * 16 + lr) * 520);
        s[ct] = __builtin_amdgcn_mfma_f32_16x16x32_bf16(qf[ks], b, s[ct], 0, 0, 0);
      }
    }

    // ---- online softmax (rows quad*4+r, cols across the 16 lanes of the quad)
    float alpha[4];
#pragma unroll
    for (int r = 0; r < 4; ++r) {
      float mx = fmaxf(s[0][r], s[1][r]);
      mx = fmaxf(mx, __shfl_xor(mx, 1));
      mx = fmaxf(mx, __shfl_xor(mx, 2));
      mx = fmaxf(mx, __shfl_xor(mx, 4));
      mx = fmaxf(mx, __shfl_xor(mx, 8));
      float mnew = fmaxf(mrow[r], mx);
      alpha[r] = EXP2F(mrow[r] - mnew);  // first iter: exp2(-inf) = 0
      mrow[r] = mnew;
      float rs = 0.f;
#pragma unroll
      for (int ct = 0; ct < 2; ++ct) {
        float p = EXP2F(s[ct][r] - mnew);
        s[ct][r] = p;
        rs += p;
      }
      rs += __shfl_xor(rs, 1);
      rs += __shfl_xor(rs, 2);
      rs += __shfl_xor(rs, 4);
      rs += __shfl_xor(rs, 8);
      lrow[r] = lrow[r] * alpha[r] + rs;
    }
    {
      bool nd = (alpha[0] < 1.f) || (alpha[1] < 1.f) || (alpha[2] < 1.f) || (alpha[3] < 1.f);
      int any = __any(nd) ? 1 : 0;
      if (lane == 0) sFlag[wave] = any;
      if (lr == 0) {
#pragma unroll
        for (int r = 0; r < 4; ++r) sAlpha[wave * 16 + quad * 4 + r] = alpha[r];
      }
    }

    // ---- P (C layout) -> shared LDS bf16 [128][36]
#pragma unroll
    for (int ct = 0; ct < 2; ++ct)
#pragma unroll
      for (int r = 0; r < 4; ++r)
        sP[(wave * 16 + quad * 4 + r) * 36 + ct * 16 + lr] = f2bf(s[ct][r]);

    __syncthreads();  // BAR_B: sP/alphas/flags visible; drains DMA(it+1)
                      // (issued a full S-phase ago -> mostly landed)

    // ---- rescale O per 16-row group (flag gated, wave-uniform branch)
#pragma unroll
    for (int rt = 0; rt < 8; ++rt) {
      if (sFlag[rt]) {
        float4 t = ld_f4(&sAlpha[rt * 16 + quad * 4]);
#pragma unroll
        for (int ct = 0; ct < 4; ++ct) {
          o[rt * 4 + ct][0] *= t.x;
          o[rt * 4 + ct][1] *= t.y;
          o[rt * 4 + ct][2] *= t.z;
          o[rt * 4 + ct][3] *= t.w;
        }
      }
    }

    // ---- O += P V (d-split): A = P rows (all 128) from sP, B = sVT rows (d)
    const unsigned short* vb = sVT[it & 1];
    short8 vf[4];
#pragma unroll
    for (int ct = 0; ct < 4; ++ct)
      vf[ct] = ld_s8(&vb[(wave * 64 + ct * 16 + lr) * 32 + quad * 8]);
#pragma unroll
    for (int rth = 0; rth < 2; ++rth) {
      short8 pa[4];
#pragma unroll
      for (int i = 0; i < 4; ++i)
        pa[i] = ld_s8(&sP[((rth * 4 + i) * 16 + lr) * 36 + quad * 8]);
#pragma unroll
      for (int ct = 0; ct < 4; ++ct) {
#pragma unroll
        for (int i = 0; i < 4; ++i)
          o[(rth * 4 + i) * 4 + ct] = __builtin_amdgcn_mfma_f32_16x16x32_bf16(
              pa[i], vf[ct], o[(rth * 4 + i) * 4 + ct], 0, 0, 0);
      }
    }
    // next BAR_A orders sP reuse and buffer swap
  }

  // ---- epilogue: unnormalized partials (d-split layout)
  unsigned short* op = Opart + (size_t)split * NN * DD;
#pragma unroll
  for (int rt = 0; rt < 8; ++rt)
#pragma unroll
    for (int ct = 0; ct < 4; ++ct) {
      int row = n0 + rt * 16 + quad * 4;
      int col = wave * 64 + ct * 16 + lr;
#pragma unroll
      for (int r = 0; r < 4; ++r)
        op[(size_t)(row + r) * DD + col] = f2bf(o[rt * 4 + ct][r]);
    }
  const int grow = n0 + wave * 16 + quad * 4;
  if (lr == 0) {
#pragma unroll
    for (int r = 0; r < 4; ++r) {
      Mpart[split * NN + grow + r] = mrow[r];
      Lpart[split * NN + grow + r] = lrow[r];
    }
  }
}

// ---------------------------------------------------------------------------
// Kernel 3: exact softmax merge of SPLITS partials. 8 elems/thread, b128 I/O.
// grid (N*D/2048), block 256.
// ---------------------------------------------------------------------------
template <int SPLITS_>
__global__ void combine_kernel(const unsigned short* __restrict__ Op,
                               const float* __restrict__ Mp,
                               const float* __restrict__ Lp,
                               float* __restrict__ out) {
  constexpr size_t NDv = (size_t)NN * DD;
  size_t base = ((size_t)blockIdx.x * 256 + threadIdx.x) * 8;
  int n = (int)(base >> 9);
  float mv[SPLITS_];
  float ms = NEG_INF;
#pragma unroll
  for (int s = 0; s < SPLITS_; ++s) {
    mv[s] = Mp[s * NN + n];
    ms = fmaxf(ms, mv[s]);
  }
  float num[8];
#pragma unroll
  for (int j = 0; j < 8; ++j) num[j] = 0.f;
  float den = 0.f;
#pragma unroll
  for (int s = 0; s < SPLITS_; ++s) {
    float w = EXP2F(mv[s] - ms);
    den += w * Lp[s * NN + n];
    uintx4 u = ld_u4(Op + s * NDv + base);
#pragma unroll
    for (int j = 0; j < 4; ++j) {
      num[2 * j]     += w * bf2f((unsigned short)(u[j] & 0xffffu));
      num[2 * j + 1] += w * bf2f((unsigned short)(u[j] >> 16));
    }
  }
  float inv = 1.f / den;
  float4 o0 = {num[0] * inv, num[1] * inv, num[2] * inv, num[3] * inv};
  float4 o1 = {num[4] * inv, num[5] * inv, num[6] * inv, num[7] * inv};
  __builtin_memcpy(__builtin_assume_aligned(out + base, 16), &o0, 16);
  __builtin_memcpy(__builtin_assume_aligned(out + base + 4, 16), &o1, 16);
}

// ---------------------------------------------------------------------------
extern "C" void kernel_launch(void* const* d_in, const int* in_sizes, int n_in,
                              void* d_out, int out_size, void* d_ws, size_t ws_size,
                              hipStream_t stream) {
  const float* x  = (const float*)d_in[0];
  const float* dx = (const float*)d_in[1];
  const float* Wq = (const float*)d_in[2];
  const float* bq = (const float*)d_in[3];
  const float* Wk = (const float*)d_in[4];
  const float* bk = (const float*)d_in[5];
  const float* Wv = (const float*)d_in[6];
  const float* bv = (const float*)d_in[7];
  float* out = (float*)d_out;

  const size_t ND = (size_t)NN * DD;          // 4,194,304
  const size_t WBE = (size_t)3 * DD * DD;     //   786,432
  unsigned short* Qb  = (unsigned short*)d_ws;     // bf16, ND (pre-scaled)
  unsigned short* Kb  = Qb + ND;                   // bf16, ND
  unsigned short* VTb = Kb + ND;                   // bf16, ND (transposed V)
  unsigned short* Wb  = VTb + ND;                  // bf16, 3*D*D
  unsigned short* Op  = Wb + WBE;                  // bf16, splits*ND partial O

  auto bytes_for = [&](size_t S) {
    return (3 * ND + WBE + S * ND) * 2 + S * (size_t)NN * 8;
  };
  const int splits = (ws_size >= bytes_for(4)) ? 4 : 2;  // ws_size fixed -> same every call
  float* Mp = (float*)(Op + (size_t)splits * ND);
  float* Lp = Mp + (size_t)splits * NN;

  hipLaunchKernelGGL(prep_w, dim3(DD * DD / 2048, 1, 3), dim3(256), 0, stream,
                     Wq, Wk, Wv, Wb);
  hipLaunchKernelGGL(qkv_proj, dim3(NN / 64, 2, 3), dim3(256), 0, stream,
                     x, dx, Wb, bq, bk, bv, Qb, Kb, VTb);
  if (splits == 4) {
    hipLaunchKernelGGL((flash_attn<4, 2>), dim3(NN / 128 * 4), dim3(512), 0, stream,
                       Qb, Kb, VTb, Op, Mp, Lp);
    hipLaunchKernelGGL(combine_kernel<4>, dim3((unsigned)(ND / 2048)), dim3(256), 0, stream,
                       Op, Mp, Lp, out);
  } else {
    hipLaunchKernelGGL((flash_attn<2, 1>), dim3(NN / 128 * 2), dim3(512), 0, stream,
                       Qb, Kb, VTb, Op, Mp, Lp);
    hipLaunchKernelGGL(combine_kernel<2>, dim3((unsigned)(ND / 2048)), dim3(256), 0, stream,
                       Op, Mp, Lp, out);
  }
}